// Round 18
// baseline (51.016 us; speedup 1.0000x reference)
//
#include <hip/hip_runtime.h>
#include <hip/hip_bf16.h>
#include <math.h>

// Problem constants
constexpr int B     = 64;      // batch
constexpr int C     = 512;     // query input dim
constexpr int D     = 128;     // key/value dim
constexpr int NKEYS = 200000;  // memory size
constexpr int K     = 8;       // top_k

// k2 decomposition
constexpr int KT     = 64;                 // keys per subtile
constexpr int NTILES = NKEYS / KT;         // 3125 (exact)
constexpr int NBLK2  = 512;                // 2 blocks/CU (proven best)
constexpr int EXTRA  = NTILES - 6 * NBLK2; // 53 blocks own a 7th tile
constexpr int KD     = 4;                  // per-lane top-list depth
constexpr int TOPSEL = 48;                 // rescore-threshold rank target
constexpr int CAP    = 512;                // max compacted candidates

typedef __attribute__((ext_vector_type(8))) short bf16x8;
typedef __attribute__((ext_vector_type(4))) float f32x4;
typedef unsigned int uint32;

// ---------------------------------------------------------------------------
template<int KK>
__device__ __forceinline__ void topk_ins(float (&tv)[KK], int (&ti)[KK], float s, int n) {
    if (s <= tv[KK - 1]) return;
    tv[KK - 1] = s; ti[KK - 1] = n;
#pragma unroll
    for (int j = KK - 1; j > 0; --j) {
        if (tv[j] > tv[j - 1]) {
            float t = tv[j]; tv[j] = tv[j - 1]; tv[j - 1] = t;
            int   u = ti[j]; ti[j] = ti[j - 1]; ti[j - 1] = u;
        }
    }
}

__device__ __forceinline__ short f2bf(float x) {
    __hip_bfloat16 h = __float2bfloat16(x);
    return __builtin_bit_cast(short, h);
}

// order-preserving float -> u32 key (ascending float == ascending unsigned)
__device__ __forceinline__ uint32 fkey(float f) {
    uint32 u = __builtin_bit_cast(uint32, f);
    return ((int)u < 0) ? ~u : (u | 0x80000000u);
}

// pack 4 f32 -> 4 bf16 (round-half-up) in 2 u32 via v_perm_b32
__device__ __forceinline__ void pack_bf4(const float4& f, uint32& lo, uint32& hi) {
    const uint32 a0 = __builtin_bit_cast(uint32, f.x) + 0x8000u;
    const uint32 a1 = __builtin_bit_cast(uint32, f.y) + 0x8000u;
    const uint32 a2 = __builtin_bit_cast(uint32, f.z) + 0x8000u;
    const uint32 a3 = __builtin_bit_cast(uint32, f.w) + 0x8000u;
    lo = __builtin_amdgcn_perm(a1, a0, 0x07060302u);
    hi = __builtin_amdgcn_perm(a3, a2, 0x07060302u);
}

// ---------------------------------------------------------------------------
// Kernel 1: q = query @ Wq + bq ; qn = l2norm(q) ; qt[d][b] fp32 + qbfT[b][d] bf16
__global__ __launch_bounds__(1024)
void k1_qproj(const float* __restrict__ query, const float* __restrict__ Wq,
              const float* __restrict__ bq, float* __restrict__ qt,
              short* __restrict__ qbfT) {
    const int b = blockIdx.x;
    const int t = threadIdx.x;
    const int d = t & 127;
    const int h = t >> 7;                       // 0..7: which eighth of C
    const float* qr = query + (size_t)b * C;

    float acc = 0.0f;
    const int c0 = h * (C / 8);
#pragma unroll 8
    for (int c = 0; c < C / 8; ++c)
        acc = fmaf(qr[c0 + c], Wq[(size_t)(c0 + c) * D + d], acc);

    __shared__ float part[8][D];
    part[h][d] = acc;
    __syncthreads();
    if (h == 0) {
        float a = bq[d];
#pragma unroll
        for (int i = 0; i < 8; ++i) a += part[i][d];
        float ss = a * a;
#pragma unroll
        for (int off = 32; off > 0; off >>= 1) ss += __shfl_xor(ss, off);
        __shared__ float w[2];
        if ((d & 63) == 0) w[d >> 6] = ss;
        __syncthreads();
        const float inv = 1.0f / fmaxf(sqrtf(w[0] + w[1]), 1e-12f);
        const float qn = a * inv;
        qt[(size_t)d * B + b] = qn;
        qbfT[(size_t)b * D + d] = f2bf(qn);
    }
}

// ---------------------------------------------------------------------------
// Kernel 2: bf16 MFMA candidate scoring. Pair-of-tiles double-buffer:
// each barrier phase stages TWO 64-key subtiles (8 float4 in flight) and
// scores two subtiles (2x MFMA cover per load batch). Same 1-deep schedule
// as the proven version -- nothing in flight across barriers.
__global__ __launch_bounds__(512, 2)
void k2_sim_topk(const float* __restrict__ keys, const float* __restrict__ imp,
                 const short* __restrict__ qbfT,
                 float* __restrict__ cval, int* __restrict__ cidx) {
    const int tid  = threadIdx.x;
    const int lane = tid & 63;
    const int w    = __builtin_amdgcn_readfirstlane(tid >> 6);  // 0..7
    const int nb   = w & 3;
    const int wm   = w >> 2;

    __shared__ short klds[2][2][KT * 128];   // [buf][half] 4 x 16 KB
    __shared__ float scales[2][2][KT];
    __shared__ float mvs[2][B][KD];
    __shared__ int   mis[2][B][KD];

    // ---- q B-fragments (held for whole kernel): batch col = lane&15 ----
    bf16x8 bq[4];
    {
        const int batch  = nb * 16 + (lane & 15);
        const char* qrow = (const char*)(qbfT + (size_t)batch * D);
        const int coff   = (lane >> 4) * 16;
#pragma unroll
        for (int ks = 0; ks < 4; ++ks)
            bq[ks] = *(const bf16x8*)(qrow + ks * 64 + coff);
    }

    float tv[KD]; int ti[KD];
#pragma unroll
    for (int j = 0; j < KD; ++j) { tv[j] = -INFINITY; ti[j] = 0; }

    const int hrow = tid >> 5;        // 0..15
    const int hcol = tid & 31;        // 0..31
    const int wbyte = hrow * 256 + ((hcol * 8) ^ ((hrow & 7) << 4));
    const bool wlane = (hcol < 4);    // scale writer lanes (1 row each)

    auto loadt = [&](int tile, float4& f0, float4& f1, float4& f2, float4& f3,
                     float& impc) {
        const float4* tb = (const float4*)(keys + (size_t)tile * KT * D);
        f0 = tb[tid]; f1 = tb[512 + tid]; f2 = tb[1024 + tid]; f3 = tb[1536 + tid];
        if (wlane) impc = imp[tile * KT + (hcol & 3) * 16 + hrow];
    };

    auto consume = [&](const float4& f0, const float4& f1, const float4& f2,
                       const float4& f3, float impc, int buf, int half) {
        float s0 = f0.x*f0.x + f0.y*f0.y + f0.z*f0.z + f0.w*f0.w;
        float s1 = f1.x*f1.x + f1.y*f1.y + f1.z*f1.z + f1.w*f1.w;
        float s2 = f2.x*f2.x + f2.y*f2.y + f2.z*f2.z + f2.w*f2.w;
        float s3 = f3.x*f3.x + f3.y*f3.y + f3.z*f3.z + f3.w*f3.w;
        const bool b0 = (lane & 1) != 0, b1 = (lane & 2) != 0;
        float t01 = b0 ? s0 : s1;
        float v01 = (b0 ? s1 : s0) + __shfl_xor(t01, 1);
        float t23 = b0 ? s2 : s3;
        float v23 = (b0 ? s3 : s2) + __shfl_xor(t23, 1);
        float t2 = b1 ? v01 : v23;
        float z  = (b1 ? v23 : v01) + __shfl_xor(t2, 2);
        z += __shfl_xor(z, 4);
        z += __shfl_xor(z, 8);
        z += __shfl_xor(z, 16);

        uint32 pk[8];
        pack_bf4(f0, pk[0], pk[1]);
        pack_bf4(f1, pk[2], pk[3]);
        pack_bf4(f2, pk[4], pk[5]);
        pack_bf4(f3, pk[6], pk[7]);

        char* kb = (char*)klds[buf][half];
        *(uint2*)(kb + wbyte        ) = make_uint2(pk[0], pk[1]);
        *(uint2*)(kb + wbyte +  4096) = make_uint2(pk[2], pk[3]);
        *(uint2*)(kb + wbyte +  8192) = make_uint2(pk[4], pk[5]);
        *(uint2*)(kb + wbyte + 12288) = make_uint2(pk[6], pk[7]);
        if (wlane)
            scales[buf][half][(hcol & 3) * 16 + hrow] = impc / fmaxf(sqrtf(z), 1e-12f);
    };

    auto score = [&](int buf, int half, int tile) {
#pragma unroll
        for (int mi = 0; mi < 2; ++mi) {
            const int mk   = wm * 2 + mi;
            const int krow = mk * 16 + (lane & 15);
            const int swk  = (krow & 7) << 4;
            const char* arow = (const char*)klds[buf][half] + krow * 256;
            const int coff = (lane >> 4) * 16;
            f32x4 acc = {0.f, 0.f, 0.f, 0.f};
#pragma unroll
            for (int ks = 0; ks < 4; ++ks) {
                bf16x8 af = *(const bf16x8*)(arow + ((ks * 64 + coff) ^ swk));
                acc = __builtin_amdgcn_mfma_f32_16x16x32_bf16(af, bq[ks], acc, 0, 0, 0);
            }
            const int kl0 = mk * 16 + (lane >> 4) * 4;
            const f32x4 scv = *(const f32x4*)&scales[buf][half][kl0];
#pragma unroll
            for (int j = 0; j < 4; ++j)
                topk_ins<KD>(tv, ti, acc[j] * scv[j], tile * KT + kl0 + j);
        }
    };

    const int bid  = blockIdx.x;
    const bool has7 = bid < EXTRA;   // 53 low blocks own tile bid + 6*NBLK2

    float4 fA0, fA1, fA2, fA3, fB0, fB1, fB2, fB3;
    float impA = 0.0f, impB = 0.0f;

    // ---- prologue: pair 0 = tiles (bid, bid+NBLK2) -> buf0 ----
    loadt(bid,          fA0, fA1, fA2, fA3, impA);
    loadt(bid + NBLK2,  fB0, fB1, fB2, fB3, impB);
    consume(fA0, fA1, fA2, fA3, impA, 0, 0);
    consume(fB0, fB1, fB2, fB3, impB, 0, 1);
    __syncthreads();

    // ---- main: 2 steady iterations (pairs 1 and 2 prefetched) ----
    int cur = 0;
#pragma unroll
    for (int p = 0; p < 2; ++p) {
        const int tA = bid + (2 * p) * NBLK2;
        const int tB = tA + NBLK2;
        const int nA = bid + (2 * p + 2) * NBLK2;
        const int nB = nA + NBLK2;
        loadt(nA, fA0, fA1, fA2, fA3, impA);
        loadt(nB, fB0, fB1, fB2, fB3, impB);
        __builtin_amdgcn_sched_barrier(0);   // loads above the MFMA section
        score(cur, 0, tA);
        score(cur, 1, tB);
        consume(fA0, fA1, fA2, fA3, impA, cur ^ 1, 0);
        consume(fB0, fB1, fB2, fB3, impB, cur ^ 1, 1);
        __syncthreads();                     // loads fully consumed: safe
        cur ^= 1;
    }

    // ---- last pair (tiles bid+4*NBLK2, bid+5*NBLK2) + optional 7th tile ----
    {
        const int tA = bid + 4 * NBLK2;
        const int tB = tA + NBLK2;
        if (has7) {
            const int t6 = bid + 6 * NBLK2;
            loadt(t6, fA0, fA1, fA2, fA3, impA);
            __builtin_amdgcn_sched_barrier(0);
            score(cur, 0, tA);
            score(cur, 1, tB);
            consume(fA0, fA1, fA2, fA3, impA, cur ^ 1, 0);
            __syncthreads();
            score(cur ^ 1, 0, t6);
        } else {
            score(cur, 0, tA);
            score(cur, 1, tB);
        }
    }

    // ---- in-wave butterfly merge across the 4 lane-groups (same batch) ----
#pragma unroll
    for (int off = 16; off <= 32; off <<= 1) {
        float ov[KD]; int oi[KD];
#pragma unroll
        for (int j = 0; j < KD; ++j) { ov[j] = __shfl_xor(tv[j], off); oi[j] = __shfl_xor(ti[j], off); }
#pragma unroll
        for (int j = 0; j < KD; ++j) topk_ins<KD>(tv, ti, ov[j], oi[j]);
    }
    __syncthreads();
    if (lane < 16) {
        const int bb = nb * 16 + lane;
#pragma unroll
        for (int j = 0; j < KD; ++j) { mvs[wm][bb][j] = tv[j]; mis[wm][bb][j] = ti[j]; }
    }
    __syncthreads();

    // ---- write candidates: wm0 top-4 ++ wm1 top-4 = 8 per batch ----
    if (tid < B) {
        const size_t base = ((size_t)tid * NBLK2 + blockIdx.x) * K;
#pragma unroll
        for (int j = 0; j < KD; ++j) {
            cval[base + j]      = mvs[0][tid][j];
            cidx[base + j]      = mis[0][tid][j];
            cval[base + KD + j] = mvs[1][tid][j];
            cidx[base + KD + j] = mis[1][tid][j];
        }
    }
}

// ---------------------------------------------------------------------------
// Kernel 3+4 fused: histogram-threshold candidate select -> exact fp32
// rescore (32 rows in flight) -> top-8 set -> softmax attention ->
// output projection (4-way split GEMV). 512 threads per batch.
__global__ __launch_bounds__(512)
void k34_select_attend(const float* __restrict__ cval, const int* __restrict__ cidx,
                       const float* __restrict__ keys, const float* __restrict__ values,
                       const float* __restrict__ imp, const float* __restrict__ qt,
                       const float* __restrict__ Wa, const float* __restrict__ ba,
                       const float* __restrict__ Wc, const float* __restrict__ bc,
                       float* __restrict__ out) {
    const int b = blockIdx.x;
    const int t = threadIdx.x;     // 0..511
    const int lane = t & 63, w = t >> 6;   // 8 waves
    constexpr int NC  = NBLK2 * K;   // 4096 candidates per batch
    constexpr int PER = NC / 512;    // 8 per thread

    __shared__ uint32 hist[4096];    // 12-bit-bin histogram (16 KB)
    __shared__ uint32 coarse[256];
    __shared__ int    candL[CAP];
    __shared__ float  simL[CAP];
    __shared__ float  qs[D];
    __shared__ int    thrBin_s, cnt_s, ncand_s;
    __shared__ int    sel[K];
    __shared__ float  part[2][K];
    __shared__ float  scores[K];
    __shared__ float  comb[D];
    __shared__ float  pc[4][D];

#pragma unroll
    for (int i = 0; i < 8; ++i) hist[t + i * 512] = 0;
    if (t == 0) cnt_s = 0;
    if (t < D) qs[t] = qt[(size_t)t * B + b];
    __syncthreads();

    // ---- phase A: load candidates, histogram their ordered keys ----
    uint32 oks[PER]; int ids[PER];
    const size_t base = (size_t)b * NC + t;
#pragma unroll
    for (int i = 0; i < PER; ++i) {
        oks[i] = fkey(cval[base + i * 512]);
        ids[i] = cidx[base + i * 512];
    }
#pragma unroll
    for (int i = 0; i < PER; ++i)
        atomicAdd(&hist[oks[i] >> 20], 1u);
    __syncthreads();

    // ---- phase A2: two-level suffix scan -> threshold bin ----
    if (t < 256) {
        uint32 cs = 0;
#pragma unroll
        for (int j = 0; j < 16; ++j) cs += hist[t * 16 + j];
        coarse[t] = cs;
    }
    __syncthreads();

    if (t < 64) {
        const uint32 g = coarse[4 * t] + coarse[4 * t + 1]
                       + coarse[4 * t + 2] + coarse[4 * t + 3];
        uint32 suf = g;
#pragma unroll
        for (int off = 1; off < 64; off <<= 1) {
            const uint32 o = __shfl_down(suf, off);
            if (t + off < 64) suf += o;
        }
        const uint32 sufnext = __shfl_down(suf, 1);
        const uint32 above0  = (t == 63) ? 0u : sufnext;
        if (suf >= TOPSEL && (t == 63 || sufnext < TOPSEL)) {
            uint32 above = above0;
            int c = 4 * t + 3;
            while (above + coarse[c] < TOPSEL) { above += coarse[c]; --c; }
            int fb = c * 16 + 15;
            while (above + hist[fb] < TOPSEL) { above += hist[fb]; --fb; }
            thrBin_s = fb;
        }
    }
    __syncthreads();
    const uint32 thrKey = (uint32)thrBin_s << 20;

    // ---- phase A3: threshold compaction ----
#pragma unroll
    for (int i = 0; i < PER; ++i) {
        if (oks[i] >= thrKey) {
            const int p = atomicAdd(&cnt_s, 1);
            if (p < CAP) candL[p] = ids[i];
        }
    }
    __syncthreads();
    if (t == 0) ncand_s = min(cnt_s, CAP);
    __syncthreads();
    const int ncand = ncand_s;

    // ---- phase B: exact fp32 rescore, 32 rows in flight (16 lanes/row) ----
    const int sub16 = lane >> 4, l16 = lane & 15;
    for (int r = w * 4 + sub16; r < ncand; r += 32) {
        const int idx = candL[r];
        const float4* kp = (const float4*)(keys + (size_t)idx * D) + l16 * 2;
        const float4 kv0 = kp[0], kv1 = kp[1];
        float dot = kv0.x * qs[8 * l16]     + kv0.y * qs[8 * l16 + 1]
                  + kv0.z * qs[8 * l16 + 2] + kv0.w * qs[8 * l16 + 3]
                  + kv1.x * qs[8 * l16 + 4] + kv1.y * qs[8 * l16 + 5]
                  + kv1.z * qs[8 * l16 + 6] + kv1.w * qs[8 * l16 + 7];
        float ss  = kv0.x*kv0.x + kv0.y*kv0.y + kv0.z*kv0.z + kv0.w*kv0.w
                  + kv1.x*kv1.x + kv1.y*kv1.y + kv1.z*kv1.z + kv1.w*kv1.w;
#pragma unroll
        for (int off = 1; off < 16; off <<= 1) {
            dot += __shfl_xor(dot, off);
            ss  += __shfl_xor(ss, off);
        }
        if (l16 == 0)
            simL[r] = dot * (1.0f / fmaxf(sqrtf(ss), 1e-12f)) * imp[idx];
    }
    __syncthreads();

    // ---- phase C: top-8 set on wave 0 (8-deep lists only) ----
    if (t < 64) {
        float fv[K]; int fi[K];
#pragma unroll
        for (int j = 0; j < K; ++j) { fv[j] = -INFINITY; fi[j] = 0; }
        for (int r = t; r < ncand; r += 64) topk_ins<K>(fv, fi, simL[r], candL[r]);
#pragma unroll
        for (int off = 1; off <= 32; off <<= 1) {
            float ov[K]; int oi[K];
#pragma unroll
            for (int j = 0; j < K; ++j) { ov[j] = __shfl_xor(fv[j], off); oi[j] = __shfl_xor(fi[j], off); }
#pragma unroll
            for (int j = 0; j < K; ++j) topk_ins<K>(fv, fi, ov[j], oi[j]);
        }
        if (t == 0) {
#pragma unroll
            for (int j = 0; j < K; ++j) sel[j] = fi[j];
        }
    }
    __syncthreads();

    // ---- attention over the 8 retrieved values ----
    const int d = t & 127;
    float v[K];
#pragma unroll
    for (int k = 0; k < K; ++k) v[k] = values[(size_t)sel[k] * D + d];

    const float wa = Wa[d];
#pragma unroll
    for (int k = 0; k < K; ++k) {
        float p = v[k] * wa;
#pragma unroll
        for (int off = 32; off > 0; off >>= 1) p += __shfl_xor(p, off);
        if (t < 128 && (t & 63) == 0) part[t >> 6][k] = p;
    }
    __syncthreads();
    if (t == 0) {
        float lg[K]; float mx = -INFINITY;
#pragma unroll
        for (int k = 0; k < K; ++k) { lg[k] = part[0][k] + part[1][k] + ba[0]; mx = fmaxf(mx, lg[k]); }
        float sum = 0.0f;
#pragma unroll
        for (int k = 0; k < K; ++k) { lg[k] = expf(lg[k] - mx); sum += lg[k]; }
        const float rs = 1.0f / sum;
#pragma unroll
        for (int k = 0; k < K; ++k) scores[k] = lg[k] * rs;
    }
    __syncthreads();

    if (t < 128) {
        float c = 0.0f;
#pragma unroll
        for (int k = 0; k < K; ++k) c = fmaf(scores[k], v[k], c);
        comb[t] = c;
    }
    __syncthreads();

    // ---- output projection: 4-way split GEMV over all 512 threads ----
    {
        const int h = t >> 7;   // 0..3
        float acc = 0.0f;
        const int d0 = h * 32;
#pragma unroll 8
        for (int dd = 0; dd < 32; ++dd)
            acc = fmaf(comb[d0 + dd], Wc[(size_t)(d0 + dd) * D + d], acc);
        pc[h][d] = acc;
    }
    __syncthreads();
    if (t < 128)
        out[(size_t)b * D + t] = bc[t] + pc[0][t] + pc[1][t] + pc[2][t] + pc[3][t];
}

// ---------------------------------------------------------------------------
extern "C" void kernel_launch(void* const* d_in, const int* in_sizes, int n_in,
                              void* d_out, int out_size, void* d_ws, size_t ws_size,
                              hipStream_t stream) {
    const float* query = (const float*)d_in[0];
    const float* keys  = (const float*)d_in[1];
    const float* vals  = (const float*)d_in[2];
    const float* imp   = (const float*)d_in[3];
    const float* Wq    = (const float*)d_in[4];
    const float* bq    = (const float*)d_in[5];
    const float* Wa    = (const float*)d_in[6];
    const float* ba    = (const float*)d_in[7];
    const float* Wc    = (const float*)d_in[8];
    const float* bc    = (const float*)d_in[9];

    float* out = (float*)d_out;

    // workspace: qt 32KB | qbfT 16KB | cval 1MB | cidx 1MB  (~2.1 MB total)
    float* qt   = (float*)d_ws;                          // 128*64 f32
    short* qbfT = (short*)(qt + (size_t)D * B);          // 64*128 bf16
    float* cval = (float*)(qbfT + (size_t)B * D);        // 64*512*8 f32
    int*   cidx = (int*)(cval + (size_t)B * NBLK2 * K);  // 64*512*8 i32

    k1_qproj<<<B, 1024, 0, stream>>>(query, Wq, bq, qt, qbfT);
    k2_sim_topk<<<NBLK2, 512, 0, stream>>>(keys, imp, qbfT, cval, cidx);
    k34_select_attend<<<B, 512, 0, stream>>>(cval, cidx, keys, vals, imp, qt,
                                             Wa, ba, Wc, bc, out);
}

// Round 19
// 47.782 us; speedup vs baseline: 1.0677x; 1.0677x over previous
//
#include <hip/hip_runtime.h>
#include <hip/hip_bf16.h>
#include <math.h>

// Problem constants
constexpr int B     = 64;      // batch
constexpr int C     = 512;     // query input dim
constexpr int D     = 128;     // key/value dim
constexpr int NKEYS = 200000;  // memory size
constexpr int K     = 8;       // top_k

// k2 decomposition
constexpr int KT     = 64;                 // keys per tile
constexpr int NTILES = NKEYS / KT;         // 3125 (exact)
constexpr int NBLK2  = 512;                // 2 blocks/CU (proven best)
constexpr int KD     = 4;                  // per-lane top-list depth
constexpr int TOPSEL = 48;                 // rescore-threshold rank target
constexpr int CAP    = 512;                // max compacted candidates

typedef __attribute__((ext_vector_type(8))) short bf16x8;
typedef __attribute__((ext_vector_type(4))) float f32x4;
typedef unsigned int uint32;

// ---------------------------------------------------------------------------
template<int KK>
__device__ __forceinline__ void topk_ins(float (&tv)[KK], int (&ti)[KK], float s, int n) {
    if (s <= tv[KK - 1]) return;
    tv[KK - 1] = s; ti[KK - 1] = n;
#pragma unroll
    for (int j = KK - 1; j > 0; --j) {
        if (tv[j] > tv[j - 1]) {
            float t = tv[j]; tv[j] = tv[j - 1]; tv[j - 1] = t;
            int   u = ti[j]; ti[j] = ti[j - 1]; ti[j - 1] = u;
        }
    }
}

__device__ __forceinline__ short f2bf(float x) {
    __hip_bfloat16 h = __float2bfloat16(x);
    return __builtin_bit_cast(short, h);
}

// order-preserving float -> u32 key (ascending float == ascending unsigned)
__device__ __forceinline__ uint32 fkey(float f) {
    uint32 u = __builtin_bit_cast(uint32, f);
    return ((int)u < 0) ? ~u : (u | 0x80000000u);
}

// pack 4 f32 -> 4 bf16 (round-half-up) in 2 u32 via v_perm_b32
__device__ __forceinline__ void pack_bf4(const float4& f, uint32& lo, uint32& hi) {
    const uint32 a0 = __builtin_bit_cast(uint32, f.x) + 0x8000u;
    const uint32 a1 = __builtin_bit_cast(uint32, f.y) + 0x8000u;
    const uint32 a2 = __builtin_bit_cast(uint32, f.z) + 0x8000u;
    const uint32 a3 = __builtin_bit_cast(uint32, f.w) + 0x8000u;
    lo = __builtin_amdgcn_perm(a1, a0, 0x07060302u);
    hi = __builtin_amdgcn_perm(a3, a2, 0x07060302u);
}

// ---------------------------------------------------------------------------
// Kernel 1: q = query @ Wq + bq ; qn = l2norm(q) ; qt[d][b] fp32 + qbfT[b][d] bf16
// 1024 threads: 8-way split of C -> 64-long serial FMA chains.
__global__ __launch_bounds__(1024)
void k1_qproj(const float* __restrict__ query, const float* __restrict__ Wq,
              const float* __restrict__ bq, float* __restrict__ qt,
              short* __restrict__ qbfT) {
    const int b = blockIdx.x;
    const int t = threadIdx.x;
    const int d = t & 127;
    const int h = t >> 7;                       // 0..7: which eighth of C
    const float* qr = query + (size_t)b * C;

    float acc = 0.0f;
    const int c0 = h * (C / 8);
#pragma unroll 8
    for (int c = 0; c < C / 8; ++c)
        acc = fmaf(qr[c0 + c], Wq[(size_t)(c0 + c) * D + d], acc);

    __shared__ float part[8][D];
    part[h][d] = acc;
    __syncthreads();
    if (h == 0) {
        float a = bq[d];
#pragma unroll
        for (int i = 0; i < 8; ++i) a += part[i][d];
        float ss = a * a;
#pragma unroll
        for (int off = 32; off > 0; off >>= 1) ss += __shfl_xor(ss, off);
        __shared__ float w[2];
        if ((d & 63) == 0) w[d >> 6] = ss;
        __syncthreads();
        const float inv = 1.0f / fmaxf(sqrtf(w[0] + w[1]), 1e-12f);
        const float qn = a * inv;
        qt[(size_t)d * B + b] = qn;
        qbfT[(size_t)b * D + d] = f2bf(qn);
    }
}

// ---------------------------------------------------------------------------
// Kernel 2: bf16 MFMA candidate scoring, standard double-buffer.
// VALU-trimmed: 5-shfl cross-value ss reduce, per-lane top-4 lists.
// (The proven 47.96 us structure: 1-deep prefetch + sched_barrier.)
__global__ __launch_bounds__(512, 2)
void k2_sim_topk(const float* __restrict__ keys, const float* __restrict__ imp,
                 const short* __restrict__ qbfT,
                 float* __restrict__ cval, int* __restrict__ cidx) {
    const int tid  = threadIdx.x;
    const int lane = tid & 63;
    const int w    = __builtin_amdgcn_readfirstlane(tid >> 6);  // 0..7
    const int nb   = w & 3;
    const int wm   = w >> 2;

    __shared__ short klds[2][KT * 128];   // 2 x 16 KB
    __shared__ float scales[2][KT];
    __shared__ float mvs[2][B][KD];
    __shared__ int   mis[2][B][KD];

    // ---- q B-fragments (held for whole kernel): batch col = lane&15 ----
    bf16x8 bq[4];
    {
        const int batch  = nb * 16 + (lane & 15);
        const char* qrow = (const char*)(qbfT + (size_t)batch * D);
        const int coff   = (lane >> 4) * 16;
#pragma unroll
        for (int ks = 0; ks < 4; ++ks)
            bq[ks] = *(const bf16x8*)(qrow + ks * 64 + coff);
    }

    float tv[KD]; int ti[KD];
#pragma unroll
    for (int j = 0; j < KD; ++j) { tv[j] = -INFINITY; ti[j] = 0; }

    const int hrow = tid >> 5;        // 0..15
    const int hcol = tid & 31;        // 0..31
    const int wbyte = hrow * 256 + ((hcol * 8) ^ ((hrow & 7) << 4));
    const bool wlane = (hcol < 4);    // scale writer lanes (1 row each)

    auto consume = [&](const float4& f0, const float4& f1, const float4& f2,
                       const float4& f3, float impc, int buf) {
        float s0 = f0.x*f0.x + f0.y*f0.y + f0.z*f0.z + f0.w*f0.w;
        float s1 = f1.x*f1.x + f1.y*f1.y + f1.z*f1.z + f1.w*f1.w;
        float s2 = f2.x*f2.x + f2.y*f2.y + f2.z*f2.z + f2.w*f2.w;
        float s3 = f3.x*f3.x + f3.y*f3.y + f3.z*f3.z + f3.w*f3.w;
        const bool b0 = (lane & 1) != 0, b1 = (lane & 2) != 0;
        float t01 = b0 ? s0 : s1;
        float v01 = (b0 ? s1 : s0) + __shfl_xor(t01, 1);
        float t23 = b0 ? s2 : s3;
        float v23 = (b0 ? s3 : s2) + __shfl_xor(t23, 1);
        float t2 = b1 ? v01 : v23;
        float z  = (b1 ? v23 : v01) + __shfl_xor(t2, 2);
        z += __shfl_xor(z, 4);
        z += __shfl_xor(z, 8);
        z += __shfl_xor(z, 16);

        uint32 pk[8];
        pack_bf4(f0, pk[0], pk[1]);
        pack_bf4(f1, pk[2], pk[3]);
        pack_bf4(f2, pk[4], pk[5]);
        pack_bf4(f3, pk[6], pk[7]);

        char* kb = (char*)klds[buf];
        *(uint2*)(kb + wbyte        ) = make_uint2(pk[0], pk[1]);
        *(uint2*)(kb + wbyte +  4096) = make_uint2(pk[2], pk[3]);
        *(uint2*)(kb + wbyte +  8192) = make_uint2(pk[4], pk[5]);
        *(uint2*)(kb + wbyte + 12288) = make_uint2(pk[6], pk[7]);
        if (wlane)
            scales[buf][(hcol & 3) * 16 + hrow] = impc / fmaxf(sqrtf(z), 1e-12f);
    };

    auto score = [&](int buf, int tile) {
#pragma unroll
        for (int mi = 0; mi < 2; ++mi) {
            const int mk   = wm * 2 + mi;
            const int krow = mk * 16 + (lane & 15);
            const int swk  = (krow & 7) << 4;
            const char* arow = (const char*)klds[buf] + krow * 256;
            const int coff = (lane >> 4) * 16;
            f32x4 acc = {0.f, 0.f, 0.f, 0.f};
#pragma unroll
            for (int ks = 0; ks < 4; ++ks) {
                bf16x8 af = *(const bf16x8*)(arow + ((ks * 64 + coff) ^ swk));
                acc = __builtin_amdgcn_mfma_f32_16x16x32_bf16(af, bq[ks], acc, 0, 0, 0);
            }
            const int kl0 = mk * 16 + (lane >> 4) * 4;
            const f32x4 scv = *(const f32x4*)&scales[buf][kl0];
#pragma unroll
            for (int j = 0; j < 4; ++j)
                topk_ins<KD>(tv, ti, acc[j] * scv[j], tile * KT + kl0 + j);
        }
    };

    int tile = blockIdx.x;
    float4 f0, f1, f2, f3;
    float impc = 0.0f;
    {
        const float4* tb = (const float4*)(keys + (size_t)tile * KT * D);
        f0 = tb[tid]; f1 = tb[512 + tid]; f2 = tb[1024 + tid]; f3 = tb[1536 + tid];
        if (wlane) impc = imp[tile * KT + (hcol & 3) * 16 + hrow];
        consume(f0, f1, f2, f3, impc, 0);
    }
    __syncthreads();

    int cur = 0;
    for (;;) {
        const int nxt = tile + NBLK2;
        const bool has_next = nxt < NTILES;

        if (has_next) {
            const float4* tb = (const float4*)(keys + (size_t)nxt * KT * D);
            f0 = tb[tid]; f1 = tb[512 + tid]; f2 = tb[1024 + tid]; f3 = tb[1536 + tid];
            if (wlane) impc = imp[nxt * KT + (hcol & 3) * 16 + hrow];
        }
        __builtin_amdgcn_sched_barrier(0);   // keep loads above the MFMA section

        score(cur, tile);

        if (!has_next) break;

        consume(f0, f1, f2, f3, impc, cur ^ 1);
        __syncthreads();                     // vmcnt already drained (consumed)
        tile = nxt;
        cur ^= 1;
    }

#pragma unroll
    for (int off = 16; off <= 32; off <<= 1) {
        float ov[KD]; int oi[KD];
#pragma unroll
        for (int j = 0; j < KD; ++j) { ov[j] = __shfl_xor(tv[j], off); oi[j] = __shfl_xor(ti[j], off); }
#pragma unroll
        for (int j = 0; j < KD; ++j) topk_ins<KD>(tv, ti, ov[j], oi[j]);
    }
    __syncthreads();
    if (lane < 16) {
        const int bb = nb * 16 + lane;
#pragma unroll
        for (int j = 0; j < KD; ++j) { mvs[wm][bb][j] = tv[j]; mis[wm][bb][j] = ti[j]; }
    }
    __syncthreads();

    if (tid < B) {
        const size_t base = ((size_t)tid * NBLK2 + blockIdx.x) * K;
#pragma unroll
        for (int j = 0; j < KD; ++j) {
            cval[base + j]      = mvs[0][tid][j];
            cidx[base + j]      = mis[0][tid][j];
            cval[base + KD + j] = mvs[1][tid][j];
            cidx[base + KD + j] = mis[1][tid][j];
        }
    }
}

// ---------------------------------------------------------------------------
// Kernel 3+4 fused: histogram-threshold candidate select -> exact fp32
// rescore (32 rows in flight) -> top-8 set -> softmax attention ->
// output projection (4-way split GEMV). 512 threads per batch.
__global__ __launch_bounds__(512)
void k34_select_attend(const float* __restrict__ cval, const int* __restrict__ cidx,
                       const float* __restrict__ keys, const float* __restrict__ values,
                       const float* __restrict__ imp, const float* __restrict__ qt,
                       const float* __restrict__ Wa, const float* __restrict__ ba,
                       const float* __restrict__ Wc, const float* __restrict__ bc,
                       float* __restrict__ out) {
    const int b = blockIdx.x;
    const int t = threadIdx.x;     // 0..511
    const int lane = t & 63, w = t >> 6;   // 8 waves
    constexpr int NC  = NBLK2 * K;   // 4096 candidates per batch
    constexpr int PER = NC / 512;    // 8 per thread

    __shared__ uint32 hist[4096];    // 12-bit-bin histogram (16 KB)
    __shared__ uint32 coarse[256];
    __shared__ int    candL[CAP];
    __shared__ float  simL[CAP];
    __shared__ float  qs[D];
    __shared__ int    thrBin_s, cnt_s, ncand_s;
    __shared__ int    sel[K];
    __shared__ float  part[2][K];
    __shared__ float  scores[K];
    __shared__ float  comb[D];
    __shared__ float  pc[4][D];

#pragma unroll
    for (int i = 0; i < 8; ++i) hist[t + i * 512] = 0;
    if (t == 0) cnt_s = 0;
    if (t < D) qs[t] = qt[(size_t)t * B + b];
    __syncthreads();

    // ---- phase A: load candidates, histogram their ordered keys ----
    uint32 oks[PER]; int ids[PER];
    const size_t base = (size_t)b * NC + t;
#pragma unroll
    for (int i = 0; i < PER; ++i) {
        oks[i] = fkey(cval[base + i * 512]);
        ids[i] = cidx[base + i * 512];
    }
#pragma unroll
    for (int i = 0; i < PER; ++i)
        atomicAdd(&hist[oks[i] >> 20], 1u);
    __syncthreads();

    // ---- phase A2: two-level suffix scan -> threshold bin ----
    if (t < 256) {
        uint32 cs = 0;
#pragma unroll
        for (int j = 0; j < 16; ++j) cs += hist[t * 16 + j];
        coarse[t] = cs;
    }
    __syncthreads();

    if (t < 64) {
        const uint32 g = coarse[4 * t] + coarse[4 * t + 1]
                       + coarse[4 * t + 2] + coarse[4 * t + 3];
        uint32 suf = g;
#pragma unroll
        for (int off = 1; off < 64; off <<= 1) {
            const uint32 o = __shfl_down(suf, off);
            if (t + off < 64) suf += o;
        }
        const uint32 sufnext = __shfl_down(suf, 1);
        const uint32 above0  = (t == 63) ? 0u : sufnext;
        if (suf >= TOPSEL && (t == 63 || sufnext < TOPSEL)) {
            uint32 above = above0;
            int c = 4 * t + 3;
            while (above + coarse[c] < TOPSEL) { above += coarse[c]; --c; }
            int fb = c * 16 + 15;
            while (above + hist[fb] < TOPSEL) { above += hist[fb]; --fb; }
            thrBin_s = fb;
        }
    }
    __syncthreads();
    const uint32 thrKey = (uint32)thrBin_s << 20;

    // ---- phase A3: threshold compaction ----
#pragma unroll
    for (int i = 0; i < PER; ++i) {
        if (oks[i] >= thrKey) {
            const int p = atomicAdd(&cnt_s, 1);
            if (p < CAP) candL[p] = ids[i];
        }
    }
    __syncthreads();
    if (t == 0) ncand_s = min(cnt_s, CAP);
    __syncthreads();
    const int ncand = ncand_s;

    // ---- phase B: exact fp32 rescore, 32 rows in flight (16 lanes/row) ----
    const int sub16 = lane >> 4, l16 = lane & 15;
    for (int r = w * 4 + sub16; r < ncand; r += 32) {
        const int idx = candL[r];
        const float4* kp = (const float4*)(keys + (size_t)idx * D) + l16 * 2;
        const float4 kv0 = kp[0], kv1 = kp[1];
        float dot = kv0.x * qs[8 * l16]     + kv0.y * qs[8 * l16 + 1]
                  + kv0.z * qs[8 * l16 + 2] + kv0.w * qs[8 * l16 + 3]
                  + kv1.x * qs[8 * l16 + 4] + kv1.y * qs[8 * l16 + 5]
                  + kv1.z * qs[8 * l16 + 6] + kv1.w * qs[8 * l16 + 7];
        float ss  = kv0.x*kv0.x + kv0.y*kv0.y + kv0.z*kv0.z + kv0.w*kv0.w
                  + kv1.x*kv1.x + kv1.y*kv1.y + kv1.z*kv1.z + kv1.w*kv1.w;
#pragma unroll
        for (int off = 1; off < 16; off <<= 1) {
            dot += __shfl_xor(dot, off);
            ss  += __shfl_xor(ss, off);
        }
        if (l16 == 0)
            simL[r] = dot * (1.0f / fmaxf(sqrtf(ss), 1e-12f)) * imp[idx];
    }
    __syncthreads();

    // ---- phase C: top-8 set on wave 0 (8-deep lists only) ----
    if (t < 64) {
        float fv[K]; int fi[K];
#pragma unroll
        for (int j = 0; j < K; ++j) { fv[j] = -INFINITY; fi[j] = 0; }
        for (int r = t; r < ncand; r += 64) topk_ins<K>(fv, fi, simL[r], candL[r]);
#pragma unroll
        for (int off = 1; off <= 32; off <<= 1) {
            float ov[K]; int oi[K];
#pragma unroll
            for (int j = 0; j < K; ++j) { ov[j] = __shfl_xor(fv[j], off); oi[j] = __shfl_xor(fi[j], off); }
#pragma unroll
            for (int j = 0; j < K; ++j) topk_ins<K>(fv, fi, ov[j], oi[j]);
        }
        if (t == 0) {
#pragma unroll
            for (int j = 0; j < K; ++j) sel[j] = fi[j];
        }
    }
    __syncthreads();

    // ---- attention over the 8 retrieved values ----
    const int d = t & 127;
    float v[K];
#pragma unroll
    for (int k = 0; k < K; ++k) v[k] = values[(size_t)sel[k] * D + d];

    const float wa = Wa[d];
#pragma unroll
    for (int k = 0; k < K; ++k) {
        float p = v[k] * wa;
#pragma unroll
        for (int off = 32; off > 0; off >>= 1) p += __shfl_xor(p, off);
        if (t < 128 && (t & 63) == 0) part[t >> 6][k] = p;
    }
    __syncthreads();
    if (t == 0) {
        float lg[K]; float mx = -INFINITY;
#pragma unroll
        for (int k = 0; k < K; ++k) { lg[k] = part[0][k] + part[1][k] + ba[0]; mx = fmaxf(mx, lg[k]); }
        float sum = 0.0f;
#pragma unroll
        for (int k = 0; k < K; ++k) { lg[k] = expf(lg[k] - mx); sum += lg[k]; }
        const float rs = 1.0f / sum;
#pragma unroll
        for (int k = 0; k < K; ++k) scores[k] = lg[k] * rs;
    }
    __syncthreads();

    if (t < 128) {
        float c = 0.0f;
#pragma unroll
        for (int k = 0; k < K; ++k) c = fmaf(scores[k], v[k], c);
        comb[t] = c;
    }
    __syncthreads();

    // ---- output projection: 4-way split GEMV over all 512 threads ----
    {
        const int h = t >> 7;   // 0..3
        float acc = 0.0f;
        const int d0 = h * 32;
#pragma unroll 8
        for (int dd = 0; dd < 32; ++dd)
            acc = fmaf(comb[d0 + dd], Wc[(size_t)(d0 + dd) * D + d], acc);
        pc[h][d] = acc;
    }
    __syncthreads();
    if (t < 128)
        out[(size_t)b * D + t] = bc[t] + pc[0][t] + pc[1][t] + pc[2][t] + pc[3][t];
}

// ---------------------------------------------------------------------------
extern "C" void kernel_launch(void* const* d_in, const int* in_sizes, int n_in,
                              void* d_out, int out_size, void* d_ws, size_t ws_size,
                              hipStream_t stream) {
    const float* query = (const float*)d_in[0];
    const float* keys  = (const float*)d_in[1];
    const float* vals  = (const float*)d_in[2];
    const float* imp   = (const float*)d_in[3];
    const float* Wq    = (const float*)d_in[4];
    const float* bq    = (const float*)d_in[5];
    const float* Wa    = (const float*)d_in[6];
    const float* ba    = (const float*)d_in[7];
    const float* Wc    = (const float*)d_in[8];
    const float* bc    = (const float*)d_in[9];

    float* out = (float*)d_out;

    // workspace: qt 32KB | qbfT 16KB | cval 1MB | cidx 1MB  (~2.1 MB total)
    float* qt   = (float*)d_ws;                          // 128*64 f32
    short* qbfT = (short*)(qt + (size_t)D * B);          // 64*128 bf16
    float* cval = (float*)(qbfT + (size_t)B * D);        // 64*512*8 f32
    int*   cidx = (int*)(cval + (size_t)B * NBLK2 * K);  // 64*512*8 i32

    k1_qproj<<<B, 1024, 0, stream>>>(query, Wq, bq, qt, qbfT);
    k2_sim_topk<<<NBLK2, 512, 0, stream>>>(keys, imp, qbfT, cval, cidx);
    k34_select_attend<<<B, 512, 0, stream>>>(cval, cidx, keys, vals, imp, qt,
                                             Wa, ba, Wc, bc, out);
}